// Round 4
// baseline (5199.975 us; speedup 1.0000x reference)
//
#include <hip/hip_runtime.h>
#include <cstddef>

typedef short bf16x8 __attribute__((ext_vector_type(8)));
typedef float f32x4 __attribute__((ext_vector_type(4)));

// fast sigmoid/tanh via v_exp_f32 + v_rcp_f32 (~1e-7 abs err, negligible vs bf16 h)
__device__ __forceinline__ float sigm(float x) {
    return __builtin_amdgcn_rcpf(1.f + __expf(-x));
}
__device__ __forceinline__ float ftanh(float x) {
    float e = __expf(2.f * x);
    return 1.f - 2.f * __builtin_amdgcn_rcpf(e + 1.f);
}

// f32 -> bf16 (round to nearest even)
__device__ __forceinline__ unsigned short f2bf(float f) {
    union { float f; unsigned u; } v; v.f = f;
    return (unsigned short)((v.u + 0x7FFFu + ((v.u >> 16) & 1u)) >> 16);
}

// lgkm-only barrier: LDS ordered, global loads/stores stay in flight (no vmcnt drain)
__device__ __forceinline__ void bar_lgkm() {
    asm volatile("s_waitcnt lgkmcnt(0)\ns_barrier" ::: "memory");
    __builtin_amdgcn_sched_barrier(0);
}

// ============================================================================
// prep_cast: one pass producing all bf16 operands.
// ============================================================================
#define N0 (20160 * 160)
#define N1 (2048 * 160)
#define N2 (2048 * 256)

__global__ __launch_bounds__(256) void prep_cast(
    const int* __restrict__ ids, const int* __restrict__ titles,
    const float* __restrict__ emb,
    const float* __restrict__ swf, const float* __restrict__ swb,
    const float* __restrict__ dwf, const float* __restrict__ dwb,
    unsigned* __restrict__ Abf, unsigned* __restrict__ Wsen,
    unsigned* __restrict__ Wdoc)
{
    int idx = blockIdx.x * 256 + threadIdx.x;
    if (idx < N0) {
        int row = idx / 160, kk = idx - row * 160;
        int id = (row < 19200) ? ids[row] : titles[row - 19200];
        float a = 0.f, b = 0.f;
        if (kk < 150) {
            const float* s = emb + (size_t)id * 300 + kk * 2;
            a = s[0]; b = s[1];
        }
        Abf[idx] = (unsigned)f2bf(a) | ((unsigned)f2bf(b) << 16);
    } else if (idx < N0 + N1) {
        int j = idx - N0;
        int row = j / 160, kk = j - row * 160;
        const float* base = (row < 1024) ? swf + (size_t)row * 300
                                         : swb + (size_t)(row - 1024) * 300;
        float a = 0.f, b = 0.f;
        if (kk < 150) { a = base[kk * 2]; b = base[kk * 2 + 1]; }
        Wsen[j] = (unsigned)f2bf(a) | ((unsigned)f2bf(b) << 16);
    } else if (idx < N0 + N1 + N2) {
        int j = idx - N0 - N1;
        int row = j >> 8, kk = j & 255;
        const float* base = (row < 1024) ? dwf + (size_t)row * 512
                                         : dwb + (size_t)(row - 1024) * 512;
        Wdoc[j] = (unsigned)f2bf(base[kk * 2]) | ((unsigned)f2bf(base[kk * 2 + 1]) << 16);
    }
}

// ============================================================================
// prep_whh: cast LSTM hidden weights to bf16, row-major [dir][1024][256].
// ============================================================================
__global__ __launch_bounds__(256) void prep_whh(
    const float* __restrict__ swf, const float* __restrict__ swb,
    const float* __restrict__ dwf, const float* __restrict__ dwb,
    unsigned* __restrict__ WS, unsigned* __restrict__ WD)
{
    int idx = blockIdx.x * 256 + threadIdx.x;   // 0 .. 524287
    const float* src; unsigned* dst;
    if (idx < 262144) {
        int j = idx; int dir = j >> 17; int rem = j & 131071;
        src = (dir ? swb : swf) + ((size_t)(rem >> 7) * 256 + (rem & 127) * 2);
        dst = WS + j;
    } else {
        int j = idx - 262144; int dir = j >> 17; int rem = j & 131071;
        src = (dir ? dwb : dwf) + ((size_t)(rem >> 7) * 256 + (rem & 127) * 2);
        dst = WD + j;
    }
    *dst = (unsigned)f2bf(src[0]) | ((unsigned)f2bf(src[1]) << 16);
}

// ============================================================================
// proj_mfma: out[M][2048] = Abf[M][Kp] @ Wbf^T + bias, output GATE-INTERLEAVED:
//   col = half*1024 + unit*4 + gate
// ============================================================================
__global__ __launch_bounds__(256) void proj_mfma(
    const unsigned short* __restrict__ Abf, int M, int Kp,
    const unsigned short* __restrict__ Wbf,
    const float* __restrict__ bf_, const float* __restrict__ bb_,
    float* __restrict__ out)
{
    __shared__ unsigned short As[128 * 40];   // pitch 80B (16B aligned)
    __shared__ unsigned short Ws[128 * 40];
    const int tid  = threadIdx.x;
    const int lane = tid & 63;
    const int w    = tid >> 6;
    const int n    = lane & 15;
    const int quad = lane >> 4;
    const int bm   = blockIdx.x * 128;
    const int by   = blockIdx.y;              // 0..15
    const int half = by >> 3;
    const int ug32 = (by & 7) * 32;
    const unsigned short* Wb = Wbf + (size_t)half * 1024 * Kp;
    const float* biasp = half ? bb_ : bf_;

    f32x4 acc[2][8];
#pragma unroll
    for (int rt = 0; rt < 2; rt++)
#pragma unroll
        for (int ct = 0; ct < 8; ct++) acc[rt][ct] = (f32x4){0.f, 0.f, 0.f, 0.f};

    const int chunks = Kp >> 5;
    for (int kc = 0; kc < chunks; kc++) {
        const int k0 = kc * 32;
#pragma unroll
        for (int j = 0; j < 2; j++) {
            int idx = j * 256 + tid;
            int arow = idx >> 2, qq = idx & 3;
            int grow = bm + arow; if (grow >= M) grow = M - 1;
            *(uint4*)&As[arow * 40 + qq * 8] =
                *(const uint4*)(Abf + (size_t)grow * Kp + k0 + qq * 8);
            int cc = idx >> 2;
            int wrow = (cc >> 5) * 256 + ug32 + (cc & 31);
            *(uint4*)&Ws[cc * 40 + qq * 8] =
                *(const uint4*)(Wb + (size_t)wrow * Kp + k0 + qq * 8);
        }
        __syncthreads();
        bf16x8 Aq[2], Bq[8];
#pragma unroll
        for (int rt = 0; rt < 2; rt++)
            Aq[rt] = *(const bf16x8*)&As[((w * 2 + rt) * 16 + n) * 40 + quad * 8];
#pragma unroll
        for (int ct = 0; ct < 8; ct++)
            Bq[ct] = *(const bf16x8*)&Ws[(ct * 16 + n) * 40 + quad * 8];
#pragma unroll
        for (int rt = 0; rt < 2; rt++)
#pragma unroll
            for (int ct = 0; ct < 8; ct++)
                acc[rt][ct] = __builtin_amdgcn_mfma_f32_16x16x32_bf16(
                    Aq[rt], Bq[ct], acc[rt][ct], 0, 0, 0);
        __syncthreads();
    }

#pragma unroll
    for (int s = 0; s < 2; s++) {
        const int uL = s * 16 + n;
        float b0 = biasp[ug32 + uL];
        float b1 = biasp[256 + ug32 + uL];
        float b2 = biasp[512 + ug32 + uL];
        float b3 = biasp[768 + ug32 + uL];
#pragma unroll
        for (int rt = 0; rt < 2; rt++) {
#pragma unroll
            for (int r = 0; r < 4; r++) {
                int row = bm + (w * 2 + rt) * 16 + quad * 4 + r;
                if (row >= M) continue;
                float4 o;
                o.x = acc[rt][0 + s][r] + b0;
                o.y = acc[rt][2 + s][r] + b1;
                o.z = acc[rt][4 + s][r] + b2;
                o.w = acc[rt][6 + s][r] + b3;
                *(float4*)(out + (size_t)row * 2048 + half * 1024 + (ug32 + uL) * 4) = o;
            }
        }
    }
}

__device__ __forceinline__ const float* sen_xbase(
    const float* xw, const float* xw_head, int grow_e, int t)
{
    if (grow_e < 640)       return xw + ((size_t)grow_e * 30 + t) * 2048;
    else if (grow_e < 1280) return xw + ((size_t)(grow_e - 640) * 30 + 29 - t) * 2048 + 1024;
    else if (grow_e < 1344) return xw_head + ((size_t)(grow_e - 1280) * 15 + t) * 2048;
    else                    return xw_head + ((size_t)(grow_e - 1344) * 15 + 14 - t) * 2048 + 1024;
}

// ============================================================================
// lstm_sen3: persistent BiLSTM, 88 pair-groups x 2 blocks x 512 thr.
// Per step: own h-half in LDS; partner half loaded DIRECTLY into MFMA A-frags
// from global (relaxed agent atomics). Sync = monotonic counter, per-wave
// increments after per-wave vmcnt drain; all threads poll. Barriers are
// lgkm-only so xw prefetch + partner loads stay in flight across them.
// h(0)=0 handled in-register (t=0 skips MFMA; gv=0).
// ============================================================================
__global__ __launch_bounds__(512, 2) void lstm_sen3(
    const float* __restrict__ xw, const float* __restrict__ xw_head,
    const unsigned short* __restrict__ WhhBf,     // [2][1024][256] bf16
    unsigned short* hbA, unsigned short* hbB,
    float* __restrict__ sentences, float* __restrict__ headings,
    unsigned* bars)
{
    const int tid  = threadIdx.x;
    const int lane = tid & 63;
    const int w    = tid >> 6;          // 0..7
    const int n    = lane & 15;
    const int quad = lane >> 4;
    const int phys = blockIdx.x;        // 0..175
    const int g    = (phys & 7) + (phys >> 4) * 8;   // 0..87
    const int p    = (phys >> 3) & 1;                // unit-half
    const int r0   = g * 16;
    const bool bwd  = (r0 >= 640 && r0 < 1280) || (r0 >= 1344);
    const bool head = (r0 >= 1280);
    const int tEnd = head ? 15 : 30;
    unsigned* cnt = bars + g * 16;
    const unsigned short* Wd = WhhBf + (bwd ? (size_t)262144 : 0);

    __shared__ unsigned short Hs[16][136];      // own half only, pitch 272B
    __shared__ float G[16][516];

    // B fragments: wave w owns local cols w*64 + ct*16 + n
    bf16x8 Bf[4][8];
#pragma unroll
    for (int ct = 0; ct < 4; ct++) {
        const int c    = ct * 16 + n;
        const int unit = p * 128 + w * 16 + (c >> 2);
        const int wrow = (c & 3) * 256 + unit;
        const unsigned short* wr = Wd + (size_t)wrow * 256;
#pragma unroll
        for (int ks = 0; ks < 8; ks++)
            Bf[ct][ks] = *(const bf16x8*)(wr + ks * 32 + quad * 8);
    }

    const int rE  = tid & 15;
    const int iE  = tid >> 4;            // 0..31
    const int ug4 = p * 128 + iE * 4;
    const int grow_e = r0 + rE;
    float cr[4] = {0.f, 0.f, 0.f, 0.f};

    // pointer-stepped xw prefetch
    const float* xptr = sen_xbase(xw, xw_head, grow_e, 0) + (size_t)ug4 * 4;
    const long long xstep = bwd ? -2048 : 2048;
    float4 xv[4];
    { const float4* xp = (const float4*)xptr;
      xv[0] = xp[0]; xv[1] = xp[1]; xv[2] = xp[2]; xv[3] = xp[3]; }

    // final h destination
    float* fdst;
    if (!head) fdst = sentences + (size_t)(bwd ? grow_e - 640 : grow_e) * 512
                      + (bwd ? 256 : 0) + ug4;
    else       fdst = headings + (size_t)(grow_e - (bwd ? 1344 : 1280)) * 512
                      + (bwd ? 256 : 0) + ug4;

    // h global store/load bases (double-buffered)
    unsigned long long* hst[2] = {
        (unsigned long long*)(hbB + (size_t)grow_e * 256 + ug4),
        (unsigned long long*)(hbA + (size_t)grow_e * 256 + ug4) };
    const unsigned long long* pld[2] = {
        (const unsigned long long*)(hbB + (size_t)(r0 + n) * 256),
        (const unsigned long long*)(hbA + (size_t)(r0 + n) * 256) };

    for (int t = 0; t < tEnd; t++) {
        if (t > 0) {
            // ---- wait for partner h(t) (stored during iter t-1) ----
            const unsigned tgt = 16u * (unsigned)t;
            while (__hip_atomic_load(cnt, __ATOMIC_RELAXED, __HIP_MEMORY_SCOPE_AGENT) < tgt) {}
            // ---- partner half -> Af regs (in flight during own-half MFMAs) ----
            bf16x8 Af[8];
            const unsigned long long* pb = pld[(t + 1) & 1];
#pragma unroll
            for (int k2 = 0; k2 < 4; k2++) {
                const int ksp = 4 * (1 - p) + k2;
                union { bf16x8 v; unsigned long long q[2]; } af;
                af.q[0] = __hip_atomic_load(pb + ksp * 8 + quad * 2,
                                            __ATOMIC_RELAXED, __HIP_MEMORY_SCOPE_AGENT);
                af.q[1] = __hip_atomic_load(pb + ksp * 8 + quad * 2 + 1,
                                            __ATOMIC_RELAXED, __HIP_MEMORY_SCOPE_AGENT);
                Af[ksp] = af.v;
            }
            // own half from LDS
#pragma unroll
            for (int k2 = 0; k2 < 4; k2++)
                Af[4 * p + k2] = *(const bf16x8*)&Hs[n][k2 * 32 + quad * 8];

            f32x4 acc[4];
#pragma unroll
            for (int ct = 0; ct < 4; ct++) acc[ct] = (f32x4){0.f, 0.f, 0.f, 0.f};
            // own-ks first (overlap partner-load latency)
#pragma unroll
            for (int k2 = 0; k2 < 4; k2++)
#pragma unroll
                for (int ct = 0; ct < 4; ct++)
                    acc[ct] = __builtin_amdgcn_mfma_f32_16x16x32_bf16(
                        Af[4 * p + k2], Bf[ct][4 * p + k2], acc[ct], 0, 0, 0);
#pragma unroll
            for (int k2 = 0; k2 < 4; k2++)
#pragma unroll
                for (int ct = 0; ct < 4; ct++)
                    acc[ct] = __builtin_amdgcn_mfma_f32_16x16x32_bf16(
                        Af[4 * (1 - p) + k2], Bf[ct][4 * (1 - p) + k2], acc[ct], 0, 0, 0);
#pragma unroll
            for (int ct = 0; ct < 4; ct++)
#pragma unroll
                for (int r = 0; r < 4; r++)
                    G[quad * 4 + r][w * 64 + ct * 16 + n] = acc[ct][r];
            bar_lgkm();       // G written -> readable
        }

        // ---- gate epilogue: 4 (row,unit) pairs per thread ----
        {
            const float4* Gp = (const float4*)&G[rE][iE * 16];
            unsigned long long hpack = 0ull;
            float hout[4];
#pragma unroll
            for (int q2 = 0; q2 < 4; q2++) {
                float4 gv;
                if (t == 0) gv = (float4){0.f, 0.f, 0.f, 0.f};
                else        gv = Gp[q2];
                float gi = gv.x + xv[q2].x;
                float gf = gv.y + xv[q2].y;
                float gg = gv.z + xv[q2].z;
                float go = gv.w + xv[q2].w;
                float cn = sigm(gf) * cr[q2] + sigm(gi) * ftanh(gg);
                float hn = sigm(go) * ftanh(cn);
                cr[q2] = cn; hout[q2] = hn;
                hpack |= ((unsigned long long)f2bf(hn)) << (16 * q2);
            }
            *(unsigned long long*)&Hs[rE][iE * 4] = hpack;     // own half -> LDS
            __hip_atomic_store(hst[t & 1], hpack,
                               __ATOMIC_RELAXED, __HIP_MEMORY_SCOPE_AGENT);
            if (t == tEnd - 1) *(float4*)fdst = *(float4*)hout;
        }

        // per-wave store drain, then signal
        asm volatile("s_waitcnt vmcnt(0)" ::: "memory");
        if (lane == 0)
            __hip_atomic_fetch_add(cnt, 1u, __ATOMIC_RELAXED, __HIP_MEMORY_SCOPE_AGENT);

        // xw prefetch for t+1 (issued after drain -> stays in flight)
        if (t + 1 < tEnd) {
            xptr += xstep;
            const float4* xp = (const float4*)xptr;
            xv[0] = xp[0]; xv[1] = xp[1]; xv[2] = xp[2]; xv[3] = xp[3];
        }
        bar_lgkm();           // Hs write -> next Af read; G reuse
    }
}

// ============================================================================
// lstm_doc3: same structure, 8 pair-groups, 10 steps. Grid 16 x 512.
// ============================================================================
__global__ __launch_bounds__(512, 2) void lstm_doc3(
    const float* __restrict__ xw,
    const unsigned short* __restrict__ WhhBf,
    unsigned short* hdA, unsigned short* hdB,
    float* __restrict__ documents,
    unsigned* bars)
{
    const int tid  = threadIdx.x;
    const int lane = tid & 63;
    const int w    = tid >> 6;
    const int n    = lane & 15;
    const int quad = lane >> 4;
    const int phys = blockIdx.x;        // 0..15
    const int g    = phys & 7;
    const int p    = (phys >> 3) & 1;
    const int r0   = g * 16;
    const bool bwd = (r0 >= 64);
    unsigned* cnt = bars + g * 16;
    const unsigned short* Wd = WhhBf + (bwd ? (size_t)262144 : 0);

    __shared__ unsigned short Hs[16][136];
    __shared__ float G[16][516];

    bf16x8 Bf[4][8];
#pragma unroll
    for (int ct = 0; ct < 4; ct++) {
        const int c    = ct * 16 + n;
        const int unit = p * 128 + w * 16 + (c >> 2);
        const int wrow = (c & 3) * 256 + unit;
        const unsigned short* wr = Wd + (size_t)wrow * 256;
#pragma unroll
        for (int ks = 0; ks < 8; ks++)
            Bf[ct][ks] = *(const bf16x8*)(wr + ks * 32 + quad * 8);
    }

    const int rE  = tid & 15;
    const int iE  = tid >> 4;
    const int ug4 = p * 128 + iE * 4;
    const int grow_e = r0 + rE;
    const int seq = bwd ? grow_e - 64 : grow_e;
    float cr[4] = {0.f, 0.f, 0.f, 0.f};

    const float* xptr = (!bwd ? xw + (size_t)seq * 10 * 2048
                              : xw + ((size_t)seq * 10 + 9) * 2048 + 1024)
                        + (size_t)ug4 * 4;
    const long long xstep = bwd ? -2048 : 2048;
    float4 xv[4];
    { const float4* xp = (const float4*)xptr;
      xv[0] = xp[0]; xv[1] = xp[1]; xv[2] = xp[2]; xv[3] = xp[3]; }

    float* dptr = documents + (size_t)(seq * 10 + (bwd ? 9 : 0)) * 512
                  + (bwd ? 256 : 0) + ug4;
    const long long dstep = bwd ? -512 : 512;

    unsigned long long* hst[2] = {
        (unsigned long long*)(hdB + (size_t)grow_e * 256 + ug4),
        (unsigned long long*)(hdA + (size_t)grow_e * 256 + ug4) };
    const unsigned long long* pld[2] = {
        (const unsigned long long*)(hdB + (size_t)(r0 + n) * 256),
        (const unsigned long long*)(hdA + (size_t)(r0 + n) * 256) };

    for (int t = 0; t < 10; t++) {
        if (t > 0) {
            const unsigned tgt = 16u * (unsigned)t;
            while (__hip_atomic_load(cnt, __ATOMIC_RELAXED, __HIP_MEMORY_SCOPE_AGENT) < tgt) {}
            bf16x8 Af[8];
            const unsigned long long* pb = pld[(t + 1) & 1];
#pragma unroll
            for (int k2 = 0; k2 < 4; k2++) {
                const int ksp = 4 * (1 - p) + k2;
                union { bf16x8 v; unsigned long long q[2]; } af;
                af.q[0] = __hip_atomic_load(pb + ksp * 8 + quad * 2,
                                            __ATOMIC_RELAXED, __HIP_MEMORY_SCOPE_AGENT);
                af.q[1] = __hip_atomic_load(pb + ksp * 8 + quad * 2 + 1,
                                            __ATOMIC_RELAXED, __HIP_MEMORY_SCOPE_AGENT);
                Af[ksp] = af.v;
            }
#pragma unroll
            for (int k2 = 0; k2 < 4; k2++)
                Af[4 * p + k2] = *(const bf16x8*)&Hs[n][k2 * 32 + quad * 8];

            f32x4 acc[4];
#pragma unroll
            for (int ct = 0; ct < 4; ct++) acc[ct] = (f32x4){0.f, 0.f, 0.f, 0.f};
#pragma unroll
            for (int k2 = 0; k2 < 4; k2++)
#pragma unroll
                for (int ct = 0; ct < 4; ct++)
                    acc[ct] = __builtin_amdgcn_mfma_f32_16x16x32_bf16(
                        Af[4 * p + k2], Bf[ct][4 * p + k2], acc[ct], 0, 0, 0);
#pragma unroll
            for (int k2 = 0; k2 < 4; k2++)
#pragma unroll
                for (int ct = 0; ct < 4; ct++)
                    acc[ct] = __builtin_amdgcn_mfma_f32_16x16x32_bf16(
                        Af[4 * (1 - p) + k2], Bf[ct][4 * (1 - p) + k2], acc[ct], 0, 0, 0);
#pragma unroll
            for (int ct = 0; ct < 4; ct++)
#pragma unroll
                for (int r = 0; r < 4; r++)
                    G[quad * 4 + r][w * 64 + ct * 16 + n] = acc[ct][r];
            bar_lgkm();
        }

        {
            const float4* Gp = (const float4*)&G[rE][iE * 16];
            unsigned long long hpack = 0ull;
            float hout[4];
#pragma unroll
            for (int q2 = 0; q2 < 4; q2++) {
                float4 gv;
                if (t == 0) gv = (float4){0.f, 0.f, 0.f, 0.f};
                else        gv = Gp[q2];
                float gi = gv.x + xv[q2].x;
                float gf = gv.y + xv[q2].y;
                float gg = gv.z + xv[q2].z;
                float go = gv.w + xv[q2].w;
                float cn = sigm(gf) * cr[q2] + sigm(gi) * ftanh(gg);
                float hn = sigm(go) * ftanh(cn);
                cr[q2] = cn; hout[q2] = hn;
                hpack |= ((unsigned long long)f2bf(hn)) << (16 * q2);
            }
            *(unsigned long long*)&Hs[rE][iE * 4] = hpack;
            __hip_atomic_store(hst[t & 1], hpack,
                               __ATOMIC_RELAXED, __HIP_MEMORY_SCOPE_AGENT);
            *(float4*)dptr = *(float4*)hout;
        }

        asm volatile("s_waitcnt vmcnt(0)" ::: "memory");
        if (lane == 0)
            __hip_atomic_fetch_add(cnt, 1u, __ATOMIC_RELAXED, __HIP_MEMORY_SCOPE_AGENT);

        if (t < 9) {
            xptr += xstep;  dptr += dstep;
            const float4* xp = (const float4*)xptr;
            xv[0] = xp[0]; xv[1] = xp[1]; xv[2] = xp[2]; xv[3] = xp[3];
        }
        bar_lgkm();
    }
}

// SourceBias: biasedBf[t] = bf16(tanh(sen[t] @ trans[u] + sb_bias[u]))
__global__ __launch_bounds__(256) void source_bias(
    const float* __restrict__ sentences, const int* __restrict__ urls,
    const float* __restrict__ trans, const float* __restrict__ sb_bias,
    unsigned* __restrict__ biasedBf)
{
    const int tkn = blockIdx.x;
    const int u = urls[tkn];
    const float2* Tm = (const float2*)(trans + (size_t)u * 512 * 512);
    __shared__ float sv[512];
    for (int i = threadIdx.x; i < 512; i += 256) sv[i] = sentences[(size_t)tkn * 512 + i];
    __syncthreads();
    const int e = threadIdx.x;
    float ax = 0.f, ay = 0.f;
#pragma unroll 4
    for (int d = 0; d < 512; d++) {
        float s = sv[d];
        float2 tv = Tm[(size_t)d * 256 + e];
        ax += s * tv.x; ay += s * tv.y;
    }
    const float2 bv = ((const float2*)(sb_bias + (size_t)u * 512))[e];
    float x = ftanh(ax + bv.x), y = ftanh(ay + bv.y);
    biasedBf[(size_t)tkn * 256 + e] = (unsigned)f2bf(x) | ((unsigned)f2bf(y) << 16);
}

// v[b,d] = sum_e attn_W[d,e] * heading[b,e]; block per b
__global__ __launch_bounds__(256) void attn_v(
    const float* __restrict__ W, const float* __restrict__ headings,
    float* __restrict__ v)
{
    const int b = blockIdx.x;
    __shared__ float hh[512];
    for (int i = threadIdx.x; i < 512; i += 256) hh[i] = headings[(size_t)b * 512 + i];
    __syncthreads();
    for (int d = threadIdx.x; d < 512; d += 256) {
        float a = 0.f;
        const float* wr = W + (size_t)d * 512;
        for (int e = 0; e < 512; e++) a += wr[e] * hh[e];
        v[(size_t)b * 512 + d] = a;
    }
}

// scores -> softmax -> doc_rep -> both MLP heads; block per batch element
__global__ __launch_bounds__(256) void attn_heads(
    const float* __restrict__ documents, const float* __restrict__ v,
    const float* __restrict__ attn_b,
    const float* __restrict__ bW1, const float* __restrict__ bb1,
    const float* __restrict__ bW2, const float* __restrict__ bb2,
    const float* __restrict__ tW1, const float* __restrict__ tb1,
    const float* __restrict__ tW2, const float* __restrict__ tb2,
    float* __restrict__ out)
{
    const int b = blockIdx.x, tid = threadIdx.x;
    const int lane = tid & 63, wv_ = tid >> 6;
    __shared__ float vv[512], dr[512], h1s[256], t1s[256], sw[12], lg[5];
    for (int i = tid; i < 512; i += 256) vv[i] = v[(size_t)b * 512 + i];
    __syncthreads();
    for (int q = 0; q < 3; q++) {
        int s = q * 4 + wv_;
        float p = 0.f;
        if (s < 10) {
            const float* dp = documents + (size_t)(b * 10 + s) * 512;
            for (int d = lane; d < 512; d += 64) p += dp[d] * vv[d];
        }
#pragma unroll
        for (int off = 32; off > 0; off >>= 1) p += __shfl_down(p, off, 64);
        if (s < 10 && lane == 0) sw[s] = p + attn_b[0];
    }
    __syncthreads();
    if (tid == 0) {
        float mx = sw[0];
        for (int s = 1; s < 10; s++) mx = fmaxf(mx, sw[s]);
        float sum = 0.f;
        for (int s = 0; s < 10; s++) { sw[s] = expf(sw[s] - mx); sum += sw[s]; }
        for (int s = 0; s < 10; s++) sw[s] /= sum;
    }
    __syncthreads();
    for (int d = tid; d < 512; d += 256) {
        float a = 0.f;
#pragma unroll
        for (int s = 0; s < 10; s++) a += sw[s] * documents[(size_t)(b * 10 + s) * 512 + d];
        dr[d] = a;
    }
    __syncthreads();
    {
        float a = bb1[tid], a2 = tb1[tid];
        const float* w1 = bW1 + (size_t)tid * 512;
        const float* w2 = tW1 + (size_t)tid * 512;
        for (int k = 0; k < 512; k++) { float x = dr[k]; a += x * w1[k]; a2 += x * w2[k]; }
        h1s[tid] = ftanh(a); t1s[tid] = ftanh(a2);
    }
    __syncthreads();
    if (tid < 5) {
        float a = bb2[tid];
        const float* wp = bW2 + (size_t)tid * 256;
        for (int k = 0; k < 256; k++) a += h1s[k] * wp[k];
        lg[tid] = ftanh(a);
    }
    if (tid == 32) {
        float a = tb2[0];
        for (int k = 0; k < 256; k++) a += t1s[k] * tW2[k];
        out[320 + b] = 1.f / (1.f + expf(-ftanh(a)));
    }
    __syncthreads();
    if (tid == 0) {
        float mx = lg[0];
        for (int j = 1; j < 5; j++) mx = fmaxf(mx, lg[j]);
        float sum = 0.f, e[5];
        for (int j = 0; j < 5; j++) { e[j] = expf(lg[j] - mx); sum += e[j]; }
        for (int j = 0; j < 5; j++) out[b * 5 + j] = e[j] / sum;
    }
}

extern "C" void kernel_launch(void* const* d_in, const int* in_sizes, int n_in,
                              void* d_out, int out_size, void* d_ws, size_t ws_size,
                              hipStream_t stream)
{
    (void)in_sizes; (void)n_in; (void)out_size; (void)ws_size;
    const int*   input_ids = (const int*)d_in[0];
    const int*   urls      = (const int*)d_in[1];
    const int*   titles    = (const int*)d_in[2];
    const float* emb       = (const float*)d_in[3];
    const float* sen_wih_f = (const float*)d_in[4];
    const float* sen_whh_f = (const float*)d_in[5];
    const float* sen_b_f   = (const float*)d_in[6];
    const float* sen_wih_b = (const float*)d_in[7];
    const float* sen_whh_b = (const float*)d_in[8];
    const float* sen_b_b   = (const float*)d_in[9];
    const float* trans     = (const float*)d_in[10];
    const float* sb_bias   = (const float*)d_in[11];
    const float* doc_wih_f = (const float*)d_in[12];
    const float* doc_whh_f = (const float*)d_in[13];
    const float* doc_b_f   = (const float*)d_in[14];
    const float* doc_wih_b = (const float*)d_in[15];
    const float* doc_whh_b = (const float*)d_in[16];
    const float* doc_b_b   = (const float*)d_in[17];
    const float* attn_W    = (const float*)d_in[18];
    const float* attn_b    = (const float*)d_in[19];
    const float* bias_W1   = (const float*)d_in[20];
    const float* bias_b1   = (const float*)d_in[21];
    const float* bias_W2   = (const float*)d_in[22];
    const float* bias_b2   = (const float*)d_in[23];
    const float* truth_W1  = (const float*)d_in[24];
    const float* truth_b1  = (const float*)d_in[25];
    const float* truth_W2  = (const float*)d_in[26];
    const float* truth_b2  = (const float*)d_in[27];
    float* out = (float*)d_out;

    float* ws = (float*)d_ws;
    float* xw_all      = ws;
    float* xw_head     = xw_all + (size_t)19200 * 2048;
    unsigned* biasedBf = (unsigned*)(ws + 0);
    float* xw_doc      = ws + 163840;
    float* documents   = ws + 1474560;
    float* vbuf        = ws + 1802240;

    float* slotB       = ws + 41287680;
    unsigned* Abf      = (unsigned*)slotB;
    float* sentences   = slotB;
    float* headings    = slotB + 327680;
    unsigned* WhhSbf   = (unsigned*)(slotB + 360448);   // [2][1024][128] u32
    unsigned* WhhDbf   = (unsigned*)(slotB + 622592);
    unsigned short* hbA = (unsigned short*)(slotB + 884736);
    unsigned short* hbB = (unsigned short*)(slotB + 1064960);
    unsigned short* hdA = (unsigned short*)(slotB + 1245184);
    unsigned short* hdB = (unsigned short*)(slotB + 1261568);
    unsigned* barsS    = (unsigned*)(slotB + 1277952);  // 88 pair counters
    unsigned* barsD    = barsS + 88 * 16;               // 8 pair counters

    unsigned* Wsen     = (unsigned*)(ws + 44513280);
    unsigned* Wdoc     = (unsigned*)(ws + 44840960);

    dim3 blk(256);

    // D1: gather + bf16 casts
    prep_cast<<<dim3((N0 + N1 + N2 + 255) / 256), blk, 0, stream>>>(
        input_ids, titles, emb, sen_wih_f, sen_wih_b, doc_wih_f, doc_wih_b,
        Abf, Wsen, Wdoc);

    // D2: sentence+title input projection
    proj_mfma<<<dim3(158, 16), blk, 0, stream>>>(
        (const unsigned short*)Abf, 20160, 320,
        (const unsigned short*)Wsen, sen_b_f, sen_b_b, xw_all);

    // bars zero + Whh bf16 cast (slot B dead after D2)
    hipMemsetAsync(barsS, 0, (88 + 8) * 16 * sizeof(unsigned), stream);
    prep_whh<<<dim3(2048), blk, 0, stream>>>(
        sen_whh_f, sen_whh_b, doc_whh_f, doc_whh_b, WhhSbf, WhhDbf);

    // D3: persistent sentence/heading BiLSTM
    lstm_sen3<<<dim3(176), dim3(512), 0, stream>>>(
        xw_all, xw_head, (const unsigned short*)WhhSbf, hbA, hbB,
        sentences, headings, barsS);

    // D4: SourceBias
    source_bias<<<dim3(640), blk, 0, stream>>>(sentences, urls, trans, sb_bias, biasedBf);

    // D5: document input projection
    proj_mfma<<<dim3(5, 16), blk, 0, stream>>>(
        (const unsigned short*)biasedBf, 640, 512,
        (const unsigned short*)Wdoc, doc_b_f, doc_b_b, xw_doc);

    // D6: persistent document BiLSTM
    lstm_doc3<<<dim3(16), dim3(512), 0, stream>>>(
        xw_doc, (const unsigned short*)WhhDbf, hdA, hdB, documents, barsD);

    // D7/D8: attention + heads
    attn_v<<<dim3(64), blk, 0, stream>>>(attn_W, headings, vbuf);
    attn_heads<<<dim3(64), blk, 0, stream>>>(documents, vbuf, attn_b,
                                             bias_W1, bias_b1, bias_W2, bias_b2,
                                             truth_W1, truth_b1, truth_W2, truth_b2,
                                             out);
}